// Round 5
// baseline (9501.623 us; speedup 1.0000x reference)
//
#include <hip/hip_runtime.h>
#include <hip/hip_fp16.h>
#include <stdint.h>

// LSTM, E=2048, B=2, T=2048, ALL I/O float32 (per reference dtypes).
// For t>=1 input==h, so gates = h @ (W_ih+W_hh)^T + (b_ih+b_hh).
// v6 = v4 (proven protocol: f32 h payload, absmax 2^-10) + pipelined poll.
//  - v5's f16 h payload FAILED accuracy (1.7e-2 > 1.1e-2): h-quantization
//    error compounds through the 2047-step recurrence. Weights stay f16
//    (one-shot quantization, verified); h payload reverted to f32.
//  - Pipelined tag-poll kept from v5: two register sets (A/B) of 8
//    LLC-direct loads each, counted s_waitcnt vmcnt(8), no s_sleep.
//    16 loads always in flight -> sampling period ~RTT/2 (v4's
//    check-sleep-reload-vmcnt(0) rounds were ~0.3us + full-RTT staleness).
//    vmcnt retires oldest-first, so static counts are safe (wave0's chk +
//    seqout stores only pad the first wait).
//  - Exit drain: final s_waitcnt vmcnt(0) asm takes ALL 16 poll registers
//    as inputs -> pins their liveness to the drain point, so the stray
//    in-flight set can never land into reallocated VGPRs (v5 latent bug).
// Kept from v4 (verified): f16 packed weights in VGPRs (v_fma_mix compute),
// fp32 h in padded LDS (stride 36 floats), wave-local polling with
// lgkmcnt-only sync, ONE __syncthreads/step, parity-buffered partials,
// c-state in registers, sc0 sc1 LLC-direct exchange, publish-before-seqout,
// fast sigmoid/tanh on the producer tail.
// Protocol: 8 B [tag|payload] chunks, tag-validated (poison 0xAAAAAAAA
// never matches tags 1..2047), relaxed, no fences.

#define E 2048
#define NBLK 256
#define NTHR 512
#define HLDS_B 2304            // padded floats per batch: 64 slices * 36
#define PLS_STRIDE 20          // floats per row slot (16 used + 4 pad)
#define PLS_PAR 640            // floats per parity: 32 rows * 20
#define SMEM_MAIN 23680
#define SMEM_PROJ 131072

typedef uint32_t u32;
typedef unsigned long long u64;

__device__ __forceinline__ float sigf(float x){
  return __builtin_amdgcn_rcpf(1.0f + __expf(-x));
}
__device__ __forceinline__ float tanhfast(float x){
  // 1 - 2/(e^{2x}+1); exp overflow -> rcp(inf)=0 -> 1; underflow -> -1.
  float e = __expf(2.0f * x);
  return 1.0f - 2.0f * __builtin_amdgcn_rcpf(e + 1.0f);
}

// one row x 8 k, both batches: 16 FMAs from 4 packed-f16 weight pairs
#define ROWFMA8(W0, W1, W2, W3, A0, A1) \
  A0 = fmaf(__low2float(W0),  p0.x, A0); A0 = fmaf(__high2float(W0), p0.y, A0); \
  A0 = fmaf(__low2float(W1),  p0.z, A0); A0 = fmaf(__high2float(W1), p0.w, A0); \
  A0 = fmaf(__low2float(W2),  p1.x, A0); A0 = fmaf(__high2float(W2), p1.y, A0); \
  A0 = fmaf(__low2float(W3),  p1.z, A0); A0 = fmaf(__high2float(W3), p1.w, A0); \
  A1 = fmaf(__low2float(W0),  q0.x, A1); A1 = fmaf(__high2float(W0), q0.y, A1); \
  A1 = fmaf(__low2float(W1),  q0.z, A1); A1 = fmaf(__high2float(W1), q0.w, A1); \
  A1 = fmaf(__low2float(W2),  q1.x, A1); A1 = fmaf(__high2float(W2), q1.y, A1); \
  A1 = fmaf(__low2float(W3),  q1.z, A1); A1 = fmaf(__high2float(W3), q1.w, A1);

// tag-check + fp32 LDS-deposit for poll slot J (UJ: sampled u64 register)
#define POLLCHK(J, UJ) \
  if (pend & (1 << J)){ \
    if ((u32)(UJ >> 32) == tag){ \
      hlds[cdst[J]] = __uint_as_float((u32)UJ); \
      pend &= ~(1 << J); \
    } \
  }

// 8 LLC-direct samples of this lane's 8 poll slots (512 B stride per slot set)
#define ISSUE8(R0, R1, R2, R3, R4, R5, R6, R7) \
  asm volatile( \
    "global_load_dwordx2 %0, %8, off sc0 sc1\n\t" \
    "global_load_dwordx2 %1, %8, off offset:512 sc0 sc1\n\t" \
    "global_load_dwordx2 %2, %8, off offset:1024 sc0 sc1\n\t" \
    "global_load_dwordx2 %3, %8, off offset:1536 sc0 sc1\n\t" \
    "global_load_dwordx2 %4, %8, off offset:2048 sc0 sc1\n\t" \
    "global_load_dwordx2 %5, %8, off offset:2560 sc0 sc1\n\t" \
    "global_load_dwordx2 %6, %8, off offset:3072 sc0 sc1\n\t" \
    "global_load_dwordx2 %7, %8, off offset:3584 sc0 sc1" \
    : "=&v"(R0), "=&v"(R1), "=&v"(R2), "=&v"(R3), \
      "=&v"(R4), "=&v"(R5), "=&v"(R6), "=&v"(R7) \
    : "v"(src) : "memory")

__global__ void __launch_bounds__(NTHR, 1) lstm_kernel(
    const float* __restrict__ xin, const float* __restrict__ Wih,
    const float* __restrict__ Whh, const float* __restrict__ bih,
    const float* __restrict__ bhh, u64* __restrict__ chk,
    float* __restrict__ seqout)
{
  extern __shared__ char smem[];
  float* hlds = (float*)smem;                    // [2][2304] = 18432 B (padded h)
  float* pls  = (float*)(smem + 18432);          // [2][640]  =  5120 B partials
  float* bias = (float*)(smem + 23552);          // [32]

  const int tid  = threadIdx.x;
  const int blk  = blockIdx.x;
  const int e0   = blk << 3;                     // this block owns h elems e0..e0+7
  const int lane = tid & 63;
  const int wv   = tid >> 6;                     // wave 0..7, k-slice [wv*256, +256)
  const int rg   = lane >> 3;                    // row group: rows rg*4..rg*4+3
  const int ksl  = lane & 7;                     // 32-k sub-slice within wave
  const int ks   = (wv << 3) + ksl;              // global 32-k slice 0..63
  const int k0   = ks << 5;

  if (tid < 32){
    const int grow = ((tid >> 3) << 11) + e0 + (tid & 7);
    bias[tid] = bih[grow] + bhh[grow];
  }
  // x for t=0, written in the padded h layout
  for (int i = tid; i < 2 * E; i += NTHR){
    const int b = i >> 11, k = i & 2047;
    hlds[b * HLDS_B + (k >> 5) * 36 + (k & 31)] = xin[i];
  }
  __syncthreads();

  const float* hb0 = hlds + ks * 36;             // batch 0, own 32-k slice
  const float* hb1 = hlds + HLDS_B + ks * 36;    // batch 1

  // ---- fused: build f16 Wc = Wih + Whh into registers (64 half2) AND
  //      compute t=0 gates = x @ W_ih^T in full fp32 (h=0 at t=0) ----
  __half2 wh[64];
  float acc0[4] = {0.f, 0.f, 0.f, 0.f};
  float acc1[4] = {0.f, 0.f, 0.f, 0.f};
  #pragma unroll
  for (int rr = 0; rr < 4; ++rr){
    const int row  = (rg << 2) + rr;             // 0..31 = gate*8 + eoff
    const int grow = ((row >> 3) << 11) + e0 + (row & 7);
    const float* pa = Wih + (size_t)grow * E + k0;
    const float* pb = Whh + (size_t)grow * E + k0;
    #pragma unroll
    for (int c = 0; c < 8; ++c){                 // 4 k per chunk
      float4 a = *(const float4*)(pa + (c << 2));
      float4 b = *(const float4*)(pb + (c << 2));
      wh[(rr << 4) + (c << 1)    ] =
        __halves2half2(__float2half_rn(a.x + b.x), __float2half_rn(a.y + b.y));
      wh[(rr << 4) + (c << 1) + 1] =
        __halves2half2(__float2half_rn(a.z + b.z), __float2half_rn(a.w + b.w));
      float4 x0 = *(const float4*)(hb0 + (c << 2));
      float4 x1 = *(const float4*)(hb1 + (c << 2));
      acc0[rr] = fmaf(a.x, x0.x, acc0[rr]); acc0[rr] = fmaf(a.y, x0.y, acc0[rr]);
      acc0[rr] = fmaf(a.z, x0.z, acc0[rr]); acc0[rr] = fmaf(a.w, x0.w, acc0[rr]);
      acc1[rr] = fmaf(a.x, x1.x, acc1[rr]); acc1[rr] = fmaf(a.y, x1.y, acc1[rr]);
      acc1[rr] = fmaf(a.z, x1.z, acc1[rr]); acc1[rr] = fmaf(a.w, x1.w, acc1[rr]);
    }
  }

  const float br = bias[lane & 31];              // hoisted (used by wave 0)
  float creg = 0.0f;                             // cell state (producer lanes)

  // wave-local poll mapping: chunk c = wv*512 + j*64 + lane, so load j is a
  // 512 B contiguous wave read (full 64 B lines -> no fetch amplification).
  // chunk c (block-relative): b=(c>>3)&1, elem e=((c>>4)<<3)|(c&7)
  int cdst[8];
  #pragma unroll
  for (int j = 0; j < 8; ++j){
    const int c = (wv << 9) + (j << 6) + lane;
    const int b = (c >> 3) & 1;
    const int e = ((c >> 4) << 3) | (c & 7);
    cdst[j] = b * HLDS_B + (e >> 5) * 36 + (e & 31);
  }
  u64* const pchk0 = chk;                        // parity 0 base
  u64* const pchk1 = chk + 4096;                 // parity 1 base

  for (int t = 0; t < 2048; ++t){
    // wave-level pre-reduce across the 8 k-sub-slices (ksl = lane bits 0..2)
    #pragma unroll
    for (int m = 1; m <= 4; m <<= 1){
      #pragma unroll
      for (int rr = 0; rr < 4; ++rr){
        acc0[rr] += __shfl_xor(acc0[rr], m, 64);
        acc1[rr] += __shfl_xor(acc1[rr], m, 64);
      }
    }
    if (ksl == 0){                               // 8 lanes/wave publish partials
      float2* pw = (float2*)(pls + (t & 1) * PLS_PAR);
      #pragma unroll
      for (int rr = 0; rr < 4; ++rr)
        pw[((rg << 2) + rr) * (PLS_STRIDE / 2) + wv] = make_float2(acc0[rr], acc1[rr]);
    }
    __syncthreads();                             // the ONLY barrier per step

    if (wv == 0){                                // reduce 8 wave-partials + update
      const int r = lane & 31;
      const int b = lane >> 5;
      const float* rp = pls + (t & 1) * PLS_PAR + r * PLS_STRIDE;
      float4 v0 = *(const float4*)(rp);
      float4 v1 = *(const float4*)(rp + 4);
      float4 v2 = *(const float4*)(rp + 8);
      float4 v3 = *(const float4*)(rp + 12);
      float s = br + (b ? (v0.y + v0.w + v1.y + v1.w + v2.y + v2.w + v3.y + v3.w)
                        : (v0.x + v0.z + v1.x + v1.z + v2.x + v2.z + v3.x + v3.z));
      const float gi = s;
      const float gf = __shfl(s, (lane + 8)  & 63, 64);
      const float gg = __shfl(s, (lane + 16) & 63, 64);
      const float go = __shfl(s, (lane + 24) & 63, 64);
      if (r < 8){
        const float cn = sigf(gf) * creg + sigf(gi) * tanhfast(gg);
        const float hn = sigf(go) * tanhfast(cn);
        creg = cn;
        if (t < 2047){                           // publish FIRST (critical path)
          const u64 pk = ((u64)(u32)(t + 1) << 32) | (u64)__float_as_uint(hn);
          u64* dst = (((t + 1) & 1) ? pchk1 : pchk0) + (blk << 4) + (b << 3) + r;
          asm volatile("global_store_dwordx2 %0, %1, off sc0 sc1"
                       :: "v"(dst), "v"(pk) : "memory");
        }
        seqout[(((size_t)b << 11) + (size_t)t) * E + e0 + r] = hn;
      }
    }
    if (t == 2047) break;

    {                                            // pipelined LLC-direct poll
      const u64* src = (((t + 1) & 1) ? pchk1 : pchk0) + (wv << 9) + lane;
      const u32 tag = (u32)(t + 1);
      u64 a0_, a1_, a2_, a3_, a4_, a5_, a6_, a7_;
      u64 b0_, b1_, b2_, b3_, b4_, b5_, b6_, b7_;
      ISSUE8(a0_, a1_, a2_, a3_, a4_, a5_, a6_, a7_);   // set A in flight
      ISSUE8(b0_, b1_, b2_, b3_, b4_, b5_, b6_, b7_);   // set B in flight
      int pend = 0xFF;
      for (;;){
        asm volatile("s_waitcnt vmcnt(8)" ::: "memory");  // A landed
        POLLCHK(0, a0_) POLLCHK(1, a1_) POLLCHK(2, a2_) POLLCHK(3, a3_)
        POLLCHK(4, a4_) POLLCHK(5, a5_) POLLCHK(6, a6_) POLLCHK(7, a7_)
        if (!pend) break;
        ISSUE8(a0_, a1_, a2_, a3_, a4_, a5_, a6_, a7_);
        asm volatile("s_waitcnt vmcnt(8)" ::: "memory");  // B landed
        POLLCHK(0, b0_) POLLCHK(1, b1_) POLLCHK(2, b2_) POLLCHK(3, b3_)
        POLLCHK(4, b4_) POLLCHK(5, b5_) POLLCHK(6, b6_) POLLCHK(7, b7_)
        if (!pend) break;
        ISSUE8(b0_, b1_, b2_, b3_, b4_, b5_, b6_, b7_);
      }
      // Drain the stray in-flight set. Listing all 16 poll regs as inputs
      // pins their liveness to this point: a late-landing load can never
      // write into a VGPR the allocator has reused (v5 latent hazard).
      asm volatile("s_waitcnt vmcnt(0)"
        :: "v"(a0_), "v"(a1_), "v"(a2_), "v"(a3_),
           "v"(a4_), "v"(a5_), "v"(a6_), "v"(a7_),
           "v"(b0_), "v"(b1_), "v"(b2_), "v"(b3_),
           "v"(b4_), "v"(b5_), "v"(b6_), "v"(b7_) : "memory");
      // own ds_writes visible to all lanes of this wave (wave-synchronous)
      asm volatile("s_waitcnt lgkmcnt(0)" ::: "memory");
      __builtin_amdgcn_sched_barrier(0);
    }

    // compute acc(t+1): h @ Wc^T, weights in f16 registers
    #pragma unroll
    for (int rr = 0; rr < 4; ++rr){ acc0[rr] = 0.f; acc1[rr] = 0.f; }
    #pragma unroll
    for (int c8 = 0; c8 < 4; ++c8){              // 8 k per chunk
      float4 p0 = *(const float4*)(hb0 + (c8 << 3));
      float4 p1 = *(const float4*)(hb0 + (c8 << 3) + 4);
      float4 q0 = *(const float4*)(hb1 + (c8 << 3));
      float4 q1 = *(const float4*)(hb1 + (c8 << 3) + 4);
      #pragma unroll
      for (int rr = 0; rr < 4; ++rr){
        ROWFMA8(wh[(rr << 4) + (c8 << 2)],     wh[(rr << 4) + (c8 << 2) + 1],
                wh[(rr << 4) + (c8 << 2) + 2], wh[(rr << 4) + (c8 << 2) + 3],
                acc0[rr], acc1[rr]);
      }
    }
  }
}

// In-place projection: out[row][n] = sum_k h[row][k]*Wout[n][k] + bout[n].
// Block owns 16 rows, staged to LDS first. 2 n-columns per pass halves the
// LDS read instruction count (proj is LDS-issue-bound at 1 wave/SIMD).
__global__ void __launch_bounds__(256, 1) proj_kernel(
    float* __restrict__ io, const float* __restrict__ Wout,
    const float* __restrict__ bout)
{
  extern __shared__ char smem[];
  float* alds = (float*)smem;                  // 16 x 2048 fp32 = 131072 B
  const int tid = threadIdx.x;
  const size_t rbase = (size_t)blockIdx.x * 16 * E;

  for (int idx = tid; idx < 8192; idx += 256){
    float4 v = *(const float4*)(io + rbase + ((size_t)idx << 2));
    *(float4*)(alds + (idx << 2)) = v;
  }
  __syncthreads();

  for (int p = 0; p < 4; ++p){
    const int n0 = (p << 8) + tid;             // column pair: n0, n0+1024
    const int n1 = n0 + 1024;
    const float* wr0 = Wout + (size_t)n0 * E;
    const float* wr1 = Wout + (size_t)n1 * E;
    float acc0[16], acc1[16];
    #pragma unroll
    for (int m = 0; m < 16; ++m){ acc0[m] = 0.0f; acc1[m] = 0.0f; }
    for (int kc = 0; kc < 256; ++kc){
      const float4 a0v = *(const float4*)(wr0 + (kc << 3));
      const float4 a1v = *(const float4*)(wr0 + (kc << 3) + 4);
      const float4 b0v = *(const float4*)(wr1 + (kc << 3));
      const float4 b1v = *(const float4*)(wr1 + (kc << 3) + 4);
      const float* ap = alds + (kc << 3);
      #pragma unroll
      for (int m = 0; m < 16; ++m){
        const float* a = ap + (m << 11);
        float4 x0 = *(const float4*)(a);
        float4 x1 = *(const float4*)(a + 4);
        acc0[m] = fmaf(a0v.x, x0.x, acc0[m]); acc0[m] = fmaf(a0v.y, x0.y, acc0[m]);
        acc0[m] = fmaf(a0v.z, x0.z, acc0[m]); acc0[m] = fmaf(a0v.w, x0.w, acc0[m]);
        acc0[m] = fmaf(a1v.x, x1.x, acc0[m]); acc0[m] = fmaf(a1v.y, x1.y, acc0[m]);
        acc0[m] = fmaf(a1v.z, x1.z, acc0[m]); acc0[m] = fmaf(a1v.w, x1.w, acc0[m]);
        acc1[m] = fmaf(b0v.x, x0.x, acc1[m]); acc1[m] = fmaf(b0v.y, x0.y, acc1[m]);
        acc1[m] = fmaf(b0v.z, x0.z, acc1[m]); acc1[m] = fmaf(b0v.w, x0.w, acc1[m]);
        acc1[m] = fmaf(b1v.x, x1.x, acc1[m]); acc1[m] = fmaf(b1v.y, x1.y, acc1[m]);
        acc1[m] = fmaf(b1v.z, x1.z, acc1[m]); acc1[m] = fmaf(b1v.w, x1.w, acc1[m]);
      }
    }
    const float bo0 = bout[n0];
    const float bo1 = bout[n1];
    #pragma unroll
    for (int m = 0; m < 16; ++m){
      io[rbase + ((size_t)m << 11) + n0] = acc0[m] + bo0;
      io[rbase + ((size_t)m << 11) + n1] = acc1[m] + bo1;
    }
  }
}

extern "C" void kernel_launch(void* const* d_in, const int* in_sizes, int n_in,
                              void* d_out, int out_size, void* d_ws, size_t ws_size,
                              hipStream_t stream)
{
  const float* xin  = (const float*)d_in[0];
  const float* Wih  = (const float*)d_in[1];
  const float* Whh  = (const float*)d_in[2];
  const float* bih  = (const float*)d_in[3];
  const float* bhh  = (const float*)d_in[4];
  const float* Wout = (const float*)d_in[5];
  const float* bout = (const float*)d_in[6];
  float* out = (float*)d_out;

  // chunk buffer: 2 parities x 4096 chunks x 8 B = 64 KB.
  // Poison 0xAAAAAAAA is never a valid tag (tags are 1..2047) -> no init pass.
  u64* chk = (u64*)d_ws;

  hipFuncSetAttribute((const void*)lstm_kernel,
                      hipFuncAttributeMaxDynamicSharedMemorySize, SMEM_MAIN);
  hipFuncSetAttribute((const void*)proj_kernel,
                      hipFuncAttributeMaxDynamicSharedMemorySize, SMEM_PROJ);

  void* args[] = { (void*)&xin, (void*)&Wih, (void*)&Whh, (void*)&bih, (void*)&bhh,
                   (void*)&chk, (void*)&out };
  hipLaunchCooperativeKernel((const void*)lstm_kernel, dim3(NBLK), dim3(NTHR),
                             args, SMEM_MAIN, stream);

  proj_kernel<<<256, 256, SMEM_PROJ, stream>>>(out, Wout, bout);
}